// Round 9
// baseline (72.169 us; speedup 1.0000x reference)
//
#include <hip/hip_runtime.h>

// Problem constants (fixed by setup_inputs)
#define B_    8
#define C_    256
#define H_    100
#define W_    152
#define HW_   15200
#define K_    128
#define PH_   7
#define PW_   7
#define GW_   14
#define NSAMP 196            // 14*14 sample grid
#define NROI  1024
#define OPB   12544          // 256*7*7 outputs per ROI
#define HOPB  6272           // half-channel outputs per ROI

typedef float f4v __attribute__((ext_vector_type(4)));

// ---- bf16 helpers (RNE) ----
__device__ __forceinline__ unsigned int rne_bf16(unsigned int u) {
    return (u + 0x7fffu + ((u >> 16) & 1u)) >> 16;
}
__device__ __forceinline__ unsigned int pack2bf16(float a, float b) {
    const unsigned int ua = __builtin_bit_cast(unsigned int, a);
    const unsigned int ub = __builtin_bit_cast(unsigned int, b);
    return (rne_bf16(ub) << 16) | rne_bf16(ua);
}

// ---------------------------------------------------------------------------
// Kernel 1: NCHW fp32 -> [B][half][HW][128] bf16.  (round-7 exact)
// Tile = 64 channels x 256 positions; cached loads (partial L3 reuse across
// replays); LDS channel-pair dwords; dwordx4 stores -> 128B segments.
// ---------------------------------------------------------------------------
#define NPT 60               // ceil(15200/256); last tile has 96 positions
__global__ __launch_bounds__(256) void nchw_to_nhwc_bf16(
    const float* __restrict__ in, unsigned int* __restrict__ out)
{
    __shared__ unsigned int tile[32][260];   // [cpair][pos], 33.3 KB

    int bid = blockIdx.x;
    const int pt = bid % NPT; bid /= NPT;
    const int ct = bid & 3;   bid >>= 2;
    const int b  = bid;
    const int c0 = ct * 64, p0 = pt * 256;
    const int np = (p0 + 256 <= HW_) ? 256 : (HW_ - p0);   // 256 or 96

    const int t    = threadIdx.x;
    const int wave = t >> 6, lane = t & 63;
    const int p    = lane * 4;

    const float* ip = in + ((size_t)b * C_ + c0) * HW_ + p0;
    if (p < np) {
        #pragma unroll
        for (int i = 0; i < 8; ++i) {
            const int cp = wave * 8 + i;      // channel pair 0..31
            const f4v v0 = *reinterpret_cast<const f4v*>(ip + (size_t)(2*cp  ) * HW_ + p);
            const f4v v1 = *reinterpret_cast<const f4v*>(ip + (size_t)(2*cp+1) * HW_ + p);
            uint4 d;
            d.x = pack2bf16(v0[0], v1[0]);
            d.y = pack2bf16(v0[1], v1[1]);
            d.z = pack2bf16(v0[2], v1[2]);
            d.w = pack2bf16(v0[3], v1[3]);
            *reinterpret_cast<uint4*>(&tile[cp][p]) = d;
        }
    }
    __syncthreads();

    // dest dword index = ((b*2 + half)*HW + p)*64 + (ct&1)*32 + cp
    const int half = ct >> 1;
    unsigned int* op = out + ((size_t)(b * 2 + half) * HW_ + p0) * 64
                           + (ct & 1) * 32;
    for (int pb = 0; pb < np; pb += 32) {          // np is a multiple of 32
        const int pp = pb + (t >> 3);
        const int cp = (t & 7) * 4;                // 4 dwords = 8 channels
        uint4 d;
        d.x = tile[cp + 0][pp];
        d.y = tile[cp + 1][pp];
        d.z = tile[cp + 2][pp];
        d.w = tile[cp + 3][pp];
        *reinterpret_cast<uint4*>(op + (size_t)pp * 64 + cp) = d;
    }
}

// ---------------------------------------------------------------------------
// Kernel 2: ROI gather from [B][half][HW][128] bf16.
// 2048 blocks x 448 threads (7 waves). Phase (= channel half) slowest-moving
// (3.9MB/XCD working set fits per-XCD L2); batch == bid&7 pins batch to XCD.
// wave == ph, 7 bins per wave -> perfect balance (round-7 had a 7-vs-6
// iteration tail) and monotone-x tap sequence within two feature rows (L1).
// Lane covers channels 2l,2l+1 via one dword -> 256B coalesced wave-loads.
// Store loop: 6272/448 = 14 exact full iterations.
// ---------------------------------------------------------------------------
__global__ __launch_bounds__(448) void roi_gather_half(
    const unsigned int* __restrict__ nhwc,   // dword view
    const float* __restrict__ rois,
    const int*   __restrict__ stride_p,
    float*       __restrict__ out)
{
    __shared__ int   s_o[NSAMP][4];
    __shared__ float s_w[NSAMP][4];
    __shared__ float s_out[HOPB];            // [cLocal*49 + bin], 25 KB

    const int bid  = blockIdx.x;
    const int half = bid >> 10;
    const int b    = bid & 7;
    const int n    = b * K_ + ((bid >> 3) & 127);
    const int t    = threadIdx.x;

    if (t < NSAMP) {
        const float scale = 1.0f / (float)(*stride_p);
        const float* box = rois + n * 4;
        const float x1 = box[0], y1 = box[1], x2 = box[2], y2 = box[3];
        const float start_w = x1 * scale - 0.5f;
        const float start_h = y1 * scale - 0.5f;
        const float bin_w = (x2 - x1) * scale * (1.0f / PW_);
        const float bin_h = (y2 - y1) * scale * (1.0f / PH_);

        const int gh = t / GW_;
        const int gw = t - gh * GW_;
        const float y = start_h + ((float)gh + 0.5f) * 0.5f * bin_h;
        const float x = start_w + ((float)gw + 0.5f) * 0.5f * bin_w;

        const bool valid = (y >= -1.0f) && (y <= (float)H_) &&
                           (x >= -1.0f) && (x <= (float)W_);

        float yc = fminf(fmaxf(y, 0.0f), (float)(H_ - 1));
        float xc = fminf(fmaxf(x, 0.0f), (float)(W_ - 1));
        const float y0f = floorf(yc);
        const float x0f = floorf(xc);
        const float ly = yc - y0f, lx = xc - x0f;
        const float hy = 1.0f - ly, hx = 1.0f - lx;
        const int y0 = (int)y0f;
        const int x0 = (int)x0f;
        const int y1i = min(y0 + 1, H_ - 1);
        const int x1i = min(x0 + 1, W_ - 1);

        const float m = valid ? 0.25f : 0.0f;  // fold 2x2 sample mean in

        s_o[t][0] = (y0  * W_ + x0 ) * 64;     // dword offsets in half-plane
        s_o[t][1] = (y0  * W_ + x1i) * 64;
        s_o[t][2] = (y1i * W_ + x0 ) * 64;
        s_o[t][3] = (y1i * W_ + x1i) * 64;
        s_w[t][0] = hy * hx * m;
        s_w[t][1] = hy * lx * m;
        s_w[t][2] = ly * hx * m;
        s_w[t][3] = ly * lx * m;
    }
    __syncthreads();

    const int wave = t >> 6, lane = t & 63;    // wave = ph (0..6)
    const unsigned int* fb = nhwc + (size_t)(b * 2 + half) * HW_ * 64;

    #pragma unroll
    for (int pw = 0; pw < PW_; ++pw) {
        const int bin = wave * 7 + pw;
        float a0 = 0.f, a1 = 0.f;
        #pragma unroll
        for (int sy = 0; sy < 2; ++sy) {
            #pragma unroll
            for (int sx = 0; sx < 2; ++sx) {
                const int si = (wave * 2 + sy) * GW_ + (pw * 2 + sx);
                #pragma unroll
                for (int j = 0; j < 4; ++j) {
                    const float w = s_w[si][j];
                    const unsigned int v = fb[s_o[si][j] + lane];
                    a0 = fmaf(w, __builtin_bit_cast(float, v << 16), a0);
                    a1 = fmaf(w, __builtin_bit_cast(float, v & 0xffff0000u), a1);
                }
            }
        }
        const int c = lane << 1;
        s_out[(c + 0) * 49 + bin] = a0;
        s_out[(c + 1) * 49 + bin] = a1;
    }
    __syncthreads();

    // sequential LDS reads + coalesced non-temporal stores (out never re-read)
    float* ob = out + (size_t)n * OPB + half * HOPB;
    #pragma unroll
    for (int it = 0; it < 14; ++it) {          // 6272 = 14 * 448 exact
        const int f = it * 448 + t;
        __builtin_nontemporal_store(s_out[f], ob + f);
    }
}

// ---------------------------------------------------------------------------
// Fallback (round-1 kernel, fp32 NCHW direct) if workspace too small.
// ---------------------------------------------------------------------------
#define CSPLIT 4
#define CPB   (C_ / CSPLIT)
#define ELEMS (CPB * PH_ * PW_)

__global__ __launch_bounds__(256) void roi_align_fallback(
    const float* __restrict__ feat,
    const float* __restrict__ rois,
    const int*   __restrict__ stride_p,
    float*       __restrict__ out)
{
    __shared__ int   s_off[NSAMP][4];
    __shared__ float s_w[NSAMP][4];

    const int blk   = blockIdx.x;
    const int n     = blk >> 2;
    const int cbase = (blk & 3) * CPB;
    const int b     = n / K_;
    const int t = threadIdx.x;

    if (t < NSAMP) {
        const float scale = 1.0f / (float)(*stride_p);
        const float* box = rois + n * 4;
        const float x1 = box[0], y1 = box[1], x2 = box[2], y2 = box[3];
        const float start_w = x1 * scale - 0.5f;
        const float start_h = y1 * scale - 0.5f;
        const float bin_w = (x2 - x1) * scale * (1.0f / PW_);
        const float bin_h = (y2 - y1) * scale * (1.0f / PH_);
        const int gh = t / GW_;
        const int gw = t - gh * GW_;
        const float y = start_h + ((float)gh + 0.5f) * 0.5f * bin_h;
        const float x = start_w + ((float)gw + 0.5f) * 0.5f * bin_w;
        const bool valid = (y >= -1.0f) && (y <= (float)H_) &&
                           (x >= -1.0f) && (x <= (float)W_);
        float yc = fminf(fmaxf(y, 0.0f), (float)(H_ - 1));
        float xc = fminf(fmaxf(x, 0.0f), (float)(W_ - 1));
        const float y0f = floorf(yc);
        const float x0f = floorf(xc);
        const float ly = yc - y0f, lx = xc - x0f;
        const float hy = 1.0f - ly, hx = 1.0f - lx;
        const int y0 = (int)y0f;
        const int x0 = (int)x0f;
        const int y1i = min(y0 + 1, H_ - 1);
        const int x1i = min(x0 + 1, W_ - 1);
        const float m = valid ? 0.25f : 0.0f;
        s_off[t][0] = y0  * W_ + x0;
        s_off[t][1] = y0  * W_ + x1i;
        s_off[t][2] = y1i * W_ + x0;
        s_off[t][3] = y1i * W_ + x1i;
        s_w[t][0] = hy * hx * m;
        s_w[t][1] = hy * lx * m;
        s_w[t][2] = ly * hx * m;
        s_w[t][3] = ly * lx * m;
    }
    __syncthreads();

    const float* fbp = feat + (size_t)b * C_ * HW_;
    float*       ob  = out  + ((size_t)n * C_ + cbase) * (PH_ * PW_);

    for (int e = t; e < ELEMS; e += 256) {
        const int c   = e / 49;
        const int bin = e - c * 49;
        const int ph  = bin / 7;
        const int pw  = bin - ph * 7;
        const float* fp = fbp + (size_t)(cbase + c) * HW_;
        float acc = 0.0f;
        #pragma unroll
        for (int sy = 0; sy < 2; ++sy) {
            #pragma unroll
            for (int sx = 0; sx < 2; ++sx) {
                const int si = (ph * 2 + sy) * GW_ + (pw * 2 + sx);
                acc += s_w[si][0] * fp[s_off[si][0]]
                     + s_w[si][1] * fp[s_off[si][1]]
                     + s_w[si][2] * fp[s_off[si][2]]
                     + s_w[si][3] * fp[s_off[si][3]];
            }
        }
        ob[e] = acc;
    }
}

extern "C" void kernel_launch(void* const* d_in, const int* in_sizes, int n_in,
                              void* d_out, int out_size, void* d_ws, size_t ws_size,
                              hipStream_t stream) {
    (void)in_sizes; (void)n_in; (void)out_size;
    const float* feat     = (const float*)d_in[0];
    const float* rois     = (const float*)d_in[1];
    const int*   stride_p = (const int*)  d_in[2];
    float*       out      = (float*)d_out;

    const size_t need = (size_t)B_ * HW_ * C_ * 2;   // 62.3 MB bf16
    if (ws_size >= need) {
        nchw_to_nhwc_bf16<<<B_ * 4 * NPT, 256, 0, stream>>>(
            feat, (unsigned int*)d_ws);
        roi_gather_half<<<2 * NROI, 448, 0, stream>>>(
            (const unsigned int*)d_ws, rois, stride_p, out);
    } else {
        roi_align_fallback<<<NROI * CSPLIT, 256, 0, stream>>>(
            feat, rois, stride_p, out);
    }
}

// Round 10
// 65.967 us; speedup vs baseline: 1.0940x; 1.0940x over previous
//
#include <hip/hip_runtime.h>

// Problem constants (fixed by setup_inputs)
#define B_    8
#define C_    256
#define H_    100
#define W_    152
#define HW_   15200
#define K_    128
#define PH_   7
#define PW_   7
#define GW_   14
#define NSAMP 196            // 14*14 sample grid
#define NROI  1024
#define OPB   12544          // 256*7*7 outputs per ROI
#define HOPB  6272           // half-channel outputs per ROI

typedef float f4v __attribute__((ext_vector_type(4)));

// ---- bf16 helpers (RNE) ----
__device__ __forceinline__ unsigned int rne_bf16(unsigned int u) {
    return (u + 0x7fffu + ((u >> 16) & 1u)) >> 16;
}
__device__ __forceinline__ unsigned int pack2bf16(float a, float b) {
    const unsigned int ua = __builtin_bit_cast(unsigned int, a);
    const unsigned int ub = __builtin_bit_cast(unsigned int, b);
    return (rne_bf16(ub) << 16) | rne_bf16(ua);
}

// ---------------------------------------------------------------------------
// Kernel 1: NCHW fp32 -> [B][half][HW][128] bf16.  (round-7 body)
// NEW decomposition: batch = bid&7 (same batch->XCD pinning as the gather, so
// batch b's ws lines live in XCD b's L2), and channel-tiles ordered so HALF 1
// is written FIRST, HALF 0 LAST. At gather launch, XCD b's L2 tail = batch
// b's half-0 plane (3.9MB < 4MB) = exactly what gather phase 0 reads.
// ---------------------------------------------------------------------------
#define NPT 60               // ceil(15200/256); last tile has 96 positions
__global__ __launch_bounds__(256) void nchw_to_nhwc_bf16(
    const float* __restrict__ in, unsigned int* __restrict__ out)
{
    __shared__ unsigned int tile[32][260];   // [cpair][pos], 33.3 KB

    const int bid = blockIdx.x;
    const int b   = bid & 7;                 // batch -> XCD (matches gather)
    const int r   = bid >> 3;                // 0..239
    const int pt  = r % NPT;
    const int ct  = ((r / NPT) + 2) & 3;     // order: ct=2,3 (half1) then 0,1 (half0)
    const int c0 = ct * 64, p0 = pt * 256;
    const int np = (p0 + 256 <= HW_) ? 256 : (HW_ - p0);   // 256 or 96

    const int t    = threadIdx.x;
    const int wave = t >> 6, lane = t & 63;
    const int p    = lane * 4;

    const float* ip = in + ((size_t)b * C_ + c0) * HW_ + p0;
    if (p < np) {
        #pragma unroll
        for (int i = 0; i < 8; ++i) {
            const int cp = wave * 8 + i;      // channel pair 0..31
            const f4v v0 = *reinterpret_cast<const f4v*>(ip + (size_t)(2*cp  ) * HW_ + p);
            const f4v v1 = *reinterpret_cast<const f4v*>(ip + (size_t)(2*cp+1) * HW_ + p);
            uint4 d;
            d.x = pack2bf16(v0[0], v1[0]);
            d.y = pack2bf16(v0[1], v1[1]);
            d.z = pack2bf16(v0[2], v1[2]);
            d.w = pack2bf16(v0[3], v1[3]);
            *reinterpret_cast<uint4*>(&tile[cp][p]) = d;
        }
    }
    __syncthreads();

    // dest dword index = ((b*2 + half)*HW + p)*64 + (ct&1)*32 + cp
    const int half = ct >> 1;
    unsigned int* op = out + ((size_t)(b * 2 + half) * HW_ + p0) * 64
                           + (ct & 1) * 32;
    for (int pb = 0; pb < np; pb += 32) {          // np is a multiple of 32
        const int pp = pb + (t >> 3);
        const int cp = (t & 7) * 4;                // 4 dwords = 8 channels
        uint4 d;
        d.x = tile[cp + 0][pp];
        d.y = tile[cp + 1][pp];
        d.z = tile[cp + 2][pp];
        d.w = tile[cp + 3][pp];
        *reinterpret_cast<uint4*>(op + (size_t)pp * 64 + cp) = d;
    }
}

// ---------------------------------------------------------------------------
// Kernel 2: ROI gather from [B][half][HW][128] bf16.  (round-7 exact)
// 2048 blocks x 512 threads; phase (= channel half) slowest-moving (3.9MB/XCD
// working set fits per-XCD L2); batch == bid&7 pins batch to XCD.
// Lane covers channels 2l,2l+1 via one dword -> 256B coalesced wave-loads.
// ---------------------------------------------------------------------------
__global__ __launch_bounds__(512) void roi_gather_half(
    const unsigned int* __restrict__ nhwc,   // dword view
    const float* __restrict__ rois,
    const int*   __restrict__ stride_p,
    float*       __restrict__ out)
{
    __shared__ int   s_o[NSAMP][4];
    __shared__ float s_w[NSAMP][4];
    __shared__ float s_out[HOPB];            // [cLocal*49 + bin], 25 KB

    const int bid  = blockIdx.x;
    const int half = bid >> 10;
    const int b    = bid & 7;
    const int n    = b * K_ + ((bid >> 3) & 127);
    const int t    = threadIdx.x;

    if (t < NSAMP) {
        const float scale = 1.0f / (float)(*stride_p);
        const float* box = rois + n * 4;
        const float x1 = box[0], y1 = box[1], x2 = box[2], y2 = box[3];
        const float start_w = x1 * scale - 0.5f;
        const float start_h = y1 * scale - 0.5f;
        const float bin_w = (x2 - x1) * scale * (1.0f / PW_);
        const float bin_h = (y2 - y1) * scale * (1.0f / PH_);

        const int gh = t / GW_;
        const int gw = t - gh * GW_;
        const float y = start_h + ((float)gh + 0.5f) * 0.5f * bin_h;
        const float x = start_w + ((float)gw + 0.5f) * 0.5f * bin_w;

        const bool valid = (y >= -1.0f) && (y <= (float)H_) &&
                           (x >= -1.0f) && (x <= (float)W_);

        float yc = fminf(fmaxf(y, 0.0f), (float)(H_ - 1));
        float xc = fminf(fmaxf(x, 0.0f), (float)(W_ - 1));
        const float y0f = floorf(yc);
        const float x0f = floorf(xc);
        const float ly = yc - y0f, lx = xc - x0f;
        const float hy = 1.0f - ly, hx = 1.0f - lx;
        const int y0 = (int)y0f;
        const int x0 = (int)x0f;
        const int y1i = min(y0 + 1, H_ - 1);
        const int x1i = min(x0 + 1, W_ - 1);

        const float m = valid ? 0.25f : 0.0f;  // fold 2x2 sample mean in

        s_o[t][0] = (y0  * W_ + x0 ) * 64;     // dword offsets in half-plane
        s_o[t][1] = (y0  * W_ + x1i) * 64;
        s_o[t][2] = (y1i * W_ + x0 ) * 64;
        s_o[t][3] = (y1i * W_ + x1i) * 64;
        s_w[t][0] = hy * hx * m;
        s_w[t][1] = hy * lx * m;
        s_w[t][2] = ly * hx * m;
        s_w[t][3] = ly * lx * m;
    }
    __syncthreads();

    const int wave = t >> 6, lane = t & 63;
    const unsigned int* fb = nhwc + (size_t)(b * 2 + half) * HW_ * 64;

    for (int bin = wave; bin < PH_ * PW_; bin += 8) {
        const int ph = bin / 7;
        const int pw = bin - ph * 7;
        float a0 = 0.f, a1 = 0.f;
        #pragma unroll
        for (int sy = 0; sy < 2; ++sy) {
            #pragma unroll
            for (int sx = 0; sx < 2; ++sx) {
                const int si = (ph * 2 + sy) * GW_ + (pw * 2 + sx);
                #pragma unroll
                for (int j = 0; j < 4; ++j) {
                    const float w = s_w[si][j];
                    const unsigned int v = fb[s_o[si][j] + lane];
                    a0 = fmaf(w, __builtin_bit_cast(float, v << 16), a0);
                    a1 = fmaf(w, __builtin_bit_cast(float, v & 0xffff0000u), a1);
                }
            }
        }
        const int c = lane << 1;
        s_out[(c + 0) * 49 + bin] = a0;
        s_out[(c + 1) * 49 + bin] = a1;
    }
    __syncthreads();

    // sequential LDS reads + coalesced non-temporal stores (out never re-read)
    float* ob = out + (size_t)n * OPB + half * HOPB;
    for (int f = t; f < HOPB; f += 512)
        __builtin_nontemporal_store(s_out[f], ob + f);
}

// ---------------------------------------------------------------------------
// Fallback (round-1 kernel, fp32 NCHW direct) if workspace too small.
// ---------------------------------------------------------------------------
#define CSPLIT 4
#define CPB   (C_ / CSPLIT)
#define ELEMS (CPB * PH_ * PW_)

__global__ __launch_bounds__(256) void roi_align_fallback(
    const float* __restrict__ feat,
    const float* __restrict__ rois,
    const int*   __restrict__ stride_p,
    float*       __restrict__ out)
{
    __shared__ int   s_off[NSAMP][4];
    __shared__ float s_w[NSAMP][4];

    const int blk   = blockIdx.x;
    const int n     = blk >> 2;
    const int cbase = (blk & 3) * CPB;
    const int b     = n / K_;
    const int t = threadIdx.x;

    if (t < NSAMP) {
        const float scale = 1.0f / (float)(*stride_p);
        const float* box = rois + n * 4;
        const float x1 = box[0], y1 = box[1], x2 = box[2], y2 = box[3];
        const float start_w = x1 * scale - 0.5f;
        const float start_h = y1 * scale - 0.5f;
        const float bin_w = (x2 - x1) * scale * (1.0f / PW_);
        const float bin_h = (y2 - y1) * scale * (1.0f / PH_);
        const int gh = t / GW_;
        const int gw = t - gh * GW_;
        const float y = start_h + ((float)gh + 0.5f) * 0.5f * bin_h;
        const float x = start_w + ((float)gw + 0.5f) * 0.5f * bin_w;
        const bool valid = (y >= -1.0f) && (y <= (float)H_) &&
                           (x >= -1.0f) && (x <= (float)W_);
        float yc = fminf(fmaxf(y, 0.0f), (float)(H_ - 1));
        float xc = fminf(fmaxf(x, 0.0f), (float)(W_ - 1));
        const float y0f = floorf(yc);
        const float x0f = floorf(xc);
        const float ly = yc - y0f, lx = xc - x0f;
        const float hy = 1.0f - ly, hx = 1.0f - lx;
        const int y0 = (int)y0f;
        const int x0 = (int)x0f;
        const int y1i = min(y0 + 1, H_ - 1);
        const int x1i = min(x0 + 1, W_ - 1);
        const float m = valid ? 0.25f : 0.0f;
        s_off[t][0] = y0  * W_ + x0;
        s_off[t][1] = y0  * W_ + x1i;
        s_off[t][2] = y1i * W_ + x0;
        s_off[t][3] = y1i * W_ + x1i;
        s_w[t][0] = hy * hx * m;
        s_w[t][1] = hy * lx * m;
        s_w[t][2] = ly * hx * m;
        s_w[t][3] = ly * lx * m;
    }
    __syncthreads();

    const float* fbp = feat + (size_t)b * C_ * HW_;
    float*       ob  = out  + ((size_t)n * C_ + cbase) * (PH_ * PW_);

    for (int e = t; e < ELEMS; e += 256) {
        const int c   = e / 49;
        const int bin = e - c * 49;
        const int ph  = bin / 7;
        const int pw  = bin - ph * 7;
        const float* fp = fbp + (size_t)(cbase + c) * HW_;
        float acc = 0.0f;
        #pragma unroll
        for (int sy = 0; sy < 2; ++sy) {
            #pragma unroll
            for (int sx = 0; sx < 2; ++sx) {
                const int si = (ph * 2 + sy) * GW_ + (pw * 2 + sx);
                acc += s_w[si][0] * fp[s_off[si][0]]
                     + s_w[si][1] * fp[s_off[si][1]]
                     + s_w[si][2] * fp[s_off[si][2]]
                     + s_w[si][3] * fp[s_off[si][3]];
            }
        }
        ob[e] = acc;
    }
}

extern "C" void kernel_launch(void* const* d_in, const int* in_sizes, int n_in,
                              void* d_out, int out_size, void* d_ws, size_t ws_size,
                              hipStream_t stream) {
    (void)in_sizes; (void)n_in; (void)out_size;
    const float* feat     = (const float*)d_in[0];
    const float* rois     = (const float*)d_in[1];
    const int*   stride_p = (const int*)  d_in[2];
    float*       out      = (float*)d_out;

    const size_t need = (size_t)B_ * HW_ * C_ * 2;   // 62.3 MB bf16
    if (ws_size >= need) {
        nchw_to_nhwc_bf16<<<B_ * 4 * NPT, 256, 0, stream>>>(
            feat, (unsigned int*)d_ws);
        roi_gather_half<<<2 * NROI, 512, 0, stream>>>(
            (const unsigned int*)d_ws, rois, stride_p, out);
    } else {
        roi_align_fallback<<<NROI * CSPLIT, 256, 0, stream>>>(
            feat, rois, stride_p, out);
    }
}

// Round 11
// 65.845 us; speedup vs baseline: 1.0960x; 1.0019x over previous
//
#include <hip/hip_runtime.h>

// Problem constants (fixed by setup_inputs)
#define B_    8
#define C_    256
#define H_    100
#define W_    152
#define HW_   15200
#define K_    128
#define PH_   7
#define PW_   7
#define GW_   14
#define NSAMP 196            // 14*14 sample grid
#define NROI  1024
#define OPB   12544          // 256*7*7 outputs per ROI
#define HOPB  6272           // half-channel outputs per ROI

typedef float f4v __attribute__((ext_vector_type(4)));

// ---- bf16 helpers (RNE) ----
__device__ __forceinline__ unsigned int rne_bf16(unsigned int u) {
    return (u + 0x7fffu + ((u >> 16) & 1u)) >> 16;
}
__device__ __forceinline__ unsigned int pack2bf16(float a, float b) {
    const unsigned int ua = __builtin_bit_cast(unsigned int, a);
    const unsigned int ub = __builtin_bit_cast(unsigned int, b);
    return (rne_bf16(ub) << 16) | rne_bf16(ua);
}

// ---------------------------------------------------------------------------
// Kernel 1: NCHW fp32 -> [B][half][HW][128] bf16.  (round-10 exact)
// batch = bid&7 (same batch->XCD pinning as gather); channel-tiles ordered
// half1-first / half0-last so XCD b's L2 tail = gather phase 0's input.
// ---------------------------------------------------------------------------
#define NPT 60               // ceil(15200/256); last tile has 96 positions
__global__ __launch_bounds__(256) void nchw_to_nhwc_bf16(
    const float* __restrict__ in, unsigned int* __restrict__ out)
{
    __shared__ unsigned int tile[32][260];   // [cpair][pos], 33.3 KB

    const int bid = blockIdx.x;
    const int b   = bid & 7;                 // batch -> XCD (matches gather)
    const int r   = bid >> 3;                // 0..239
    const int pt  = r % NPT;
    const int ct  = ((r / NPT) + 2) & 3;     // order: ct=2,3 (half1) then 0,1 (half0)
    const int c0 = ct * 64, p0 = pt * 256;
    const int np = (p0 + 256 <= HW_) ? 256 : (HW_ - p0);   // 256 or 96

    const int t    = threadIdx.x;
    const int wave = t >> 6, lane = t & 63;
    const int p    = lane * 4;

    const float* ip = in + ((size_t)b * C_ + c0) * HW_ + p0;
    if (p < np) {
        #pragma unroll
        for (int i = 0; i < 8; ++i) {
            const int cp = wave * 8 + i;      // channel pair 0..31
            const f4v v0 = *reinterpret_cast<const f4v*>(ip + (size_t)(2*cp  ) * HW_ + p);
            const f4v v1 = *reinterpret_cast<const f4v*>(ip + (size_t)(2*cp+1) * HW_ + p);
            uint4 d;
            d.x = pack2bf16(v0[0], v1[0]);
            d.y = pack2bf16(v0[1], v1[1]);
            d.z = pack2bf16(v0[2], v1[2]);
            d.w = pack2bf16(v0[3], v1[3]);
            *reinterpret_cast<uint4*>(&tile[cp][p]) = d;
        }
    }
    __syncthreads();

    // dest dword index = ((b*2 + half)*HW + p)*64 + (ct&1)*32 + cp
    const int half = ct >> 1;
    unsigned int* op = out + ((size_t)(b * 2 + half) * HW_ + p0) * 64
                           + (ct & 1) * 32;
    for (int pb = 0; pb < np; pb += 32) {          // np is a multiple of 32
        const int pp = pb + (t >> 3);
        const int cp = (t & 7) * 4;                // 4 dwords = 8 channels
        uint4 d;
        d.x = tile[cp + 0][pp];
        d.y = tile[cp + 1][pp];
        d.z = tile[cp + 2][pp];
        d.w = tile[cp + 3][pp];
        *reinterpret_cast<uint4*>(op + (size_t)pp * 64 + cp) = d;
    }
}

// ---------------------------------------------------------------------------
// Kernel 2: ROI gather from [B][half][HW][128] bf16.  (round-10 base)
// SINGLE CHANGE vs round 10: descriptors packed as int4/float4 so each
// sample costs 2x ds_read_b128 broadcast instead of 8x ds_read_b32
// (32 -> 8 LDS issues per bin per wave).
// ---------------------------------------------------------------------------
__global__ __launch_bounds__(512) void roi_gather_half(
    const unsigned int* __restrict__ nhwc,   // dword view
    const float* __restrict__ rois,
    const int*   __restrict__ stride_p,
    float*       __restrict__ out)
{
    __shared__ int4   s_o4[NSAMP];
    __shared__ float4 s_w4[NSAMP];
    __shared__ float  s_out[HOPB];           // [cLocal*49 + bin], 25 KB

    const int bid  = blockIdx.x;
    const int half = bid >> 10;
    const int b    = bid & 7;
    const int n    = b * K_ + ((bid >> 3) & 127);
    const int t    = threadIdx.x;

    if (t < NSAMP) {
        const float scale = 1.0f / (float)(*stride_p);
        const float* box = rois + n * 4;
        const float x1 = box[0], y1 = box[1], x2 = box[2], y2 = box[3];
        const float start_w = x1 * scale - 0.5f;
        const float start_h = y1 * scale - 0.5f;
        const float bin_w = (x2 - x1) * scale * (1.0f / PW_);
        const float bin_h = (y2 - y1) * scale * (1.0f / PH_);

        const int gh = t / GW_;
        const int gw = t - gh * GW_;
        const float y = start_h + ((float)gh + 0.5f) * 0.5f * bin_h;
        const float x = start_w + ((float)gw + 0.5f) * 0.5f * bin_w;

        const bool valid = (y >= -1.0f) && (y <= (float)H_) &&
                           (x >= -1.0f) && (x <= (float)W_);

        float yc = fminf(fmaxf(y, 0.0f), (float)(H_ - 1));
        float xc = fminf(fmaxf(x, 0.0f), (float)(W_ - 1));
        const float y0f = floorf(yc);
        const float x0f = floorf(xc);
        const float ly = yc - y0f, lx = xc - x0f;
        const float hy = 1.0f - ly, hx = 1.0f - lx;
        const int y0 = (int)y0f;
        const int x0 = (int)x0f;
        const int y1i = min(y0 + 1, H_ - 1);
        const int x1i = min(x0 + 1, W_ - 1);

        const float m = valid ? 0.25f : 0.0f;  // fold 2x2 sample mean in

        s_o4[t] = make_int4((y0  * W_ + x0 ) * 64,   // dword offsets
                            (y0  * W_ + x1i) * 64,
                            (y1i * W_ + x0 ) * 64,
                            (y1i * W_ + x1i) * 64);
        s_w4[t] = make_float4(hy * hx * m, hy * lx * m,
                              ly * hx * m, ly * lx * m);
    }
    __syncthreads();

    const int wave = t >> 6, lane = t & 63;
    const unsigned int* fb = nhwc + (size_t)(b * 2 + half) * HW_ * 64;

    for (int bin = wave; bin < PH_ * PW_; bin += 8) {
        const int ph = bin / 7;
        const int pw = bin - ph * 7;
        float a0 = 0.f, a1 = 0.f;
        #pragma unroll
        for (int sy = 0; sy < 2; ++sy) {
            #pragma unroll
            for (int sx = 0; sx < 2; ++sx) {
                const int si = (ph * 2 + sy) * GW_ + (pw * 2 + sx);
                const int4   o4 = s_o4[si];
                const float4 w4 = s_w4[si];
                const unsigned int v0 = fb[o4.x + lane];
                const unsigned int v1 = fb[o4.y + lane];
                const unsigned int v2 = fb[o4.z + lane];
                const unsigned int v3 = fb[o4.w + lane];
                a0 = fmaf(w4.x, __builtin_bit_cast(float, v0 << 16), a0);
                a1 = fmaf(w4.x, __builtin_bit_cast(float, v0 & 0xffff0000u), a1);
                a0 = fmaf(w4.y, __builtin_bit_cast(float, v1 << 16), a0);
                a1 = fmaf(w4.y, __builtin_bit_cast(float, v1 & 0xffff0000u), a1);
                a0 = fmaf(w4.z, __builtin_bit_cast(float, v2 << 16), a0);
                a1 = fmaf(w4.z, __builtin_bit_cast(float, v2 & 0xffff0000u), a1);
                a0 = fmaf(w4.w, __builtin_bit_cast(float, v3 << 16), a0);
                a1 = fmaf(w4.w, __builtin_bit_cast(float, v3 & 0xffff0000u), a1);
            }
        }
        const int c = lane << 1;
        s_out[(c + 0) * 49 + bin] = a0;
        s_out[(c + 1) * 49 + bin] = a1;
    }
    __syncthreads();

    // sequential LDS reads + coalesced non-temporal stores (out never re-read)
    float* ob = out + (size_t)n * OPB + half * HOPB;
    for (int f = t; f < HOPB; f += 512)
        __builtin_nontemporal_store(s_out[f], ob + f);
}

// ---------------------------------------------------------------------------
// Fallback (round-1 kernel, fp32 NCHW direct) if workspace too small.
// ---------------------------------------------------------------------------
#define CSPLIT 4
#define CPB   (C_ / CSPLIT)
#define ELEMS (CPB * PH_ * PW_)

__global__ __launch_bounds__(256) void roi_align_fallback(
    const float* __restrict__ feat,
    const float* __restrict__ rois,
    const int*   __restrict__ stride_p,
    float*       __restrict__ out)
{
    __shared__ int   s_off[NSAMP][4];
    __shared__ float s_w[NSAMP][4];

    const int blk   = blockIdx.x;
    const int n     = blk >> 2;
    const int cbase = (blk & 3) * CPB;
    const int b     = n / K_;
    const int t = threadIdx.x;

    if (t < NSAMP) {
        const float scale = 1.0f / (float)(*stride_p);
        const float* box = rois + n * 4;
        const float x1 = box[0], y1 = box[1], x2 = box[2], y2 = box[3];
        const float start_w = x1 * scale - 0.5f;
        const float start_h = y1 * scale - 0.5f;
        const float bin_w = (x2 - x1) * scale * (1.0f / PW_);
        const float bin_h = (y2 - y1) * scale * (1.0f / PH_);
        const int gh = t / GW_;
        const int gw = t - gh * GW_;
        const float y = start_h + ((float)gh + 0.5f) * 0.5f * bin_h;
        const float x = start_w + ((float)gw + 0.5f) * 0.5f * bin_w;
        const bool valid = (y >= -1.0f) && (y <= (float)H_) &&
                           (x >= -1.0f) && (x <= (float)W_);
        float yc = fminf(fmaxf(y, 0.0f), (float)(H_ - 1));
        float xc = fminf(fmaxf(x, 0.0f), (float)(W_ - 1));
        const float y0f = floorf(yc);
        const float x0f = floorf(xc);
        const float ly = yc - y0f, lx = xc - x0f;
        const float hy = 1.0f - ly, hx = 1.0f - lx;
        const int y0 = (int)y0f;
        const int x0 = (int)x0f;
        const int y1i = min(y0 + 1, H_ - 1);
        const int x1i = min(x0 + 1, W_ - 1);
        const float m = valid ? 0.25f : 0.0f;
        s_off[t][0] = y0  * W_ + x0;
        s_off[t][1] = y0  * W_ + x1i;
        s_off[t][2] = y1i * W_ + x0;
        s_off[t][3] = y1i * W_ + x1i;
        s_w[t][0] = hy * hx * m;
        s_w[t][1] = hy * lx * m;
        s_w[t][2] = ly * hx * m;
        s_w[t][3] = ly * lx * m;
    }
    __syncthreads();

    const float* fbp = feat + (size_t)b * C_ * HW_;
    float*       ob  = out  + ((size_t)n * C_ + cbase) * (PH_ * PW_);

    for (int e = t; e < ELEMS; e += 256) {
        const int c   = e / 49;
        const int bin = e - c * 49;
        const int ph  = bin / 7;
        const int pw  = bin - ph * 7;
        const float* fp = fbp + (size_t)(cbase + c) * HW_;
        float acc = 0.0f;
        #pragma unroll
        for (int sy = 0; sy < 2; ++sy) {
            #pragma unroll
            for (int sx = 0; sx < 2; ++sx) {
                const int si = (ph * 2 + sy) * GW_ + (pw * 2 + sx);
                acc += s_w[si][0] * fp[s_off[si][0]]
                     + s_w[si][1] * fp[s_off[si][1]]
                     + s_w[si][2] * fp[s_off[si][2]]
                     + s_w[si][3] * fp[s_off[si][3]];
            }
        }
        ob[e] = acc;
    }
}

extern "C" void kernel_launch(void* const* d_in, const int* in_sizes, int n_in,
                              void* d_out, int out_size, void* d_ws, size_t ws_size,
                              hipStream_t stream) {
    (void)in_sizes; (void)n_in; (void)out_size;
    const float* feat     = (const float*)d_in[0];
    const float* rois     = (const float*)d_in[1];
    const int*   stride_p = (const int*)  d_in[2];
    float*       out      = (float*)d_out;

    const size_t need = (size_t)B_ * HW_ * C_ * 2;   // 62.3 MB bf16
    if (ws_size >= need) {
        nchw_to_nhwc_bf16<<<B_ * 4 * NPT, 256, 0, stream>>>(
            feat, (unsigned int*)d_ws);
        roi_gather_half<<<2 * NROI, 512, 0, stream>>>(
            (const unsigned int*)d_ws, rois, stride_p, out);
    } else {
        roi_align_fallback<<<NROI * CSPLIT, 256, 0, stream>>>(
            feat, rois, stride_p, out);
    }
}